// Round 1
// baseline (152.999 us; speedup 1.0000x reference)
//
#include <hip/hip_runtime.h>
#include <hip/hip_bf16.h>

#define B_ 128
#define L_ 196
#define D_ 1024
#define M_ (B_*L_)   // 25088

typedef __attribute__((ext_vector_type(8))) short short8v;
typedef __attribute__((ext_vector_type(4))) float f32x4;
typedef unsigned short ushort_t;

// d_ws layout (bytes), all 256-aligned. Total ≈ 60.3 MB.
#define OFF_ATTBF   0UL          // 25088*1024*2 = 51,380,224
#define OFF_WBF     51380224UL   // 1024*1024*2  =  2,097,152
#define OFF_A2      53477376UL   // 128*2048*2   =    524,288   [x|h] bf16
#define OFF_W2      54001664UL   // 1024*2048*2  =  4,194,304   [Wi|Wh] bf16
#define OFF_C       58195968UL   // 128*1024*4   =    524,288   c[b,e] fp32
#define OFF_SPART   58720256UL   // 25088*16*4   =  1,605,632   score partials

__device__ inline unsigned short f2bf(float f) {
  // round-to-nearest-even bf16 (inputs are finite)
  unsigned int u = __float_as_uint(f);
  unsigned int r = (u + 0x7fffu + ((u >> 16) & 1u)) >> 16;
  return (unsigned short)r;
}

// ---------------- convert: fp32 -> bf16 staging buffers ----------------
__global__ void convert_kernel(const float* __restrict__ att, const float* __restrict__ Wa,
                               const float* __restrict__ x,   const float* __restrict__ h,
                               const float* __restrict__ Wi,  const float* __restrict__ Wh,
                               ushort_t* __restrict__ att_bf, ushort_t* __restrict__ W_bf,
                               ushort_t* __restrict__ A2,     ushort_t* __restrict__ W2) {
  const int n0 = (B_*L_*D_)/4;   // 6,422,528 float4 of att
  const int n1 = (D_*D_)/4;      //   262,144 float4 of each 1024x1024 W
  const int n2 = (B_*D_)/4;      //    32,768 float4 of x or h
  const int total = n0 + n1 + 2*n2 + 2*n1;
  for (int idx = blockIdx.x*blockDim.x + threadIdx.x; idx < total;
       idx += gridDim.x*blockDim.x) {
    const float4* src; ushort_t* dst;
    int i = idx;
    if (i < n0)               { src = (const float4*)att + i; dst = att_bf + (size_t)i*4; }
    else if ((i -= n0) < n1)  { src = (const float4*)Wa  + i; dst = W_bf  + (size_t)i*4; }
    else if ((i -= n1) < n2)  { int b = i>>8, k4 = i&255; src = (const float4*)x  + i; dst = A2 + b*2048 + k4*4; }
    else if ((i -= n2) < n2)  { int b = i>>8, k4 = i&255; src = (const float4*)h  + i; dst = A2 + b*2048 + 1024 + k4*4; }
    else if ((i -= n2) < n1)  { int e = i>>8, k4 = i&255; src = (const float4*)Wi + i; dst = W2 + e*2048 + k4*4; }
    else { i -= n1;             int e = i>>8, k4 = i&255; src = (const float4*)Wh + i; dst = W2 + e*2048 + 1024 + k4*4; }
    float4 v = *src;
    ushort4 o; o.x = f2bf(v.x); o.y = f2bf(v.y); o.z = f2bf(v.z); o.w = f2bf(v.w);
    *(ushort4*)dst = o;
  }
}

// ---------------- GEMM: C[m,e] = sum_k A[m,k]*Bm[e,k], bf16 MFMA ----------------
// Tile 128x128, K_STEP=64, 4 waves (2x2 of 64x64). LDS tiles [128][64] bf16,
// XOR-swizzled (phys_chunk = chunk ^ (row&7)) via pre-swizzled global source
// (rule #21: global_load_lds dest must be linear wave-uniform-base + lane*16).
__device__ inline void stage_tile(const ushort_t* __restrict__ g, int row0, int K, int k0,
                                  ushort_t* ldst, int t) {
  #pragma unroll
  for (int it = 0; it < 4; ++it) {
    int linear = it*4096 + t*16;          // byte offset in 16KB tile this lane fills
    int r = linear >> 7;                  // row (128B per row)
    int c = (t & 7) ^ (r & 7);            // logical 16B chunk this phys slot holds
    const ushort_t* src = g + (size_t)(row0 + r)*K + k0 + c*8;
    ushort_t* dst = ldst + ((it*4096 + ((t & 192) << 4)) >> 1);  // wave-uniform base
    __builtin_amdgcn_global_load_lds((const __attribute__((address_space(1))) void*)src,
                                     (__attribute__((address_space(3))) void*)dst,
                                     16, 0, 0);
  }
}

__device__ inline short8v ldfrag(const ushort_t* tile, int row, int c) {
  int phys = c ^ (row & 7);
  return *(const short8v*)(tile + row*64 + phys*8);   // ds_read_b128
}

template<int EPI>
__global__ __launch_bounds__(256) void gemm_kernel(
    const ushort_t* __restrict__ Amat, const ushort_t* __restrict__ Bmat, int K,
    const float* __restrict__ ba, const float* __restrict__ bh, const float* __restrict__ bi,
    const float* __restrict__ cmat, const float* __restrict__ wd,
    float* __restrict__ outc, float* __restrict__ spart) {
  __shared__ ushort_t lds[32768];   // 64 KB: A0@0 B0@8192 A1@16384 B1@24576 (elems)
  int bid = blockIdx.x;
  int nwg = gridDim.x;              // multiple of 8
  int cpx = nwg >> 3;
  int swz = (bid & 7)*cpx + (bid >> 3);   // XCD-chunked: same-m e-blocks share an XCD L2
  int m_blk = swz >> 3, e_blk = swz & 7;  // N is always 1024 -> 8 e-blocks
  int m0 = m_blk*128, e0 = e_blk*128;
  int t = threadIdx.x, lane = t & 63, w = t >> 6;
  int wm = w >> 1, we = w & 1;
  int lrow = lane & 15;     // frag row
  int lk = lane >> 4;       // frag k-group

  f32x4 acc[4][4];
  #pragma unroll
  for (int i = 0; i < 4; ++i)
    #pragma unroll
    for (int j = 0; j < 4; ++j) acc[i][j] = (f32x4){0.f, 0.f, 0.f, 0.f};

  stage_tile(Amat, m0, K, 0, lds, t);
  stage_tile(Bmat, e0, K, 0, lds + 8192, t);
  __syncthreads();

  int nk = K >> 6;
  for (int kt = 0; kt < nk; ++kt) {
    int cur = kt & 1;
    if (kt + 1 < nk) {
      stage_tile(Amat, m0, K, (kt+1) << 6, lds + (cur^1)*16384, t);
      stage_tile(Bmat, e0, K, (kt+1) << 6, lds + (cur^1)*16384 + 8192, t);
    }
    const ushort_t* At = lds + cur*16384;
    const ushort_t* Bt = At + 8192;
    #pragma unroll
    for (int hh = 0; hh < 2; ++hh) {
      short8v af[4], bfv[4];
      #pragma unroll
      for (int i = 0; i < 4; ++i) af[i]  = ldfrag(At, wm*64 + i*16 + lrow, hh*4 + lk);
      #pragma unroll
      for (int j = 0; j < 4; ++j) bfv[j] = ldfrag(Bt, we*64 + j*16 + lrow, hh*4 + lk);
      #pragma unroll
      for (int i = 0; i < 4; ++i)
        #pragma unroll
        for (int j = 0; j < 4; ++j)
          acc[i][j] = __builtin_amdgcn_mfma_f32_16x16x32_bf16(af[i], bfv[j], acc[i][j], 0, 0, 0);
    }
    __syncthreads();
  }

  if (EPI == 0) {
    // c[b,e] = acc + ba+bh+bi  (m is b here; M=128, one m-block)
    #pragma unroll
    for (int i = 0; i < 4; ++i) {
      int m = m0 + wm*64 + i*16 + lk*4;
      #pragma unroll
      for (int j = 0; j < 4; ++j) {
        int e = e0 + we*64 + j*16 + lrow;
        float bsum = ba[e] + bh[e] + bi[e];
        #pragma unroll
        for (int r = 0; r < 4; ++r)
          outc[(m + r)*1024 + e] = acc[i][j][r] + bsum;
      }
    }
  } else {
    // partial score: sum_e tanh(acc + c[b,e]) * wd[e]; deterministic (no atomics)
    #pragma unroll
    for (int i = 0; i < 4; ++i) {
      #pragma unroll
      for (int r = 0; r < 4; ++r) {
        int m = m0 + wm*64 + i*16 + lk*4 + r;
        int bb = (int)((unsigned)m / 196u);
        float partial = 0.f;
        #pragma unroll
        for (int j = 0; j < 4; ++j) {
          int e = e0 + we*64 + j*16 + lrow;
          float v = acc[i][j][r] + cmat[bb*1024 + e];
          float ex = __expf(2.f*v);                 // tanh = 1 - 2/(e^2x+1)
          partial += (1.f - 2.f/(ex + 1.f)) * wd[e];
        }
        #pragma unroll
        for (int off = 1; off < 16; off <<= 1)
          partial += __shfl_xor(partial, off);      // reduce 16 e-lanes (same lk)
        if (lrow == 0)
          spart[(size_t)m*16 + e_blk*2 + we] = partial;
      }
    }
  }
}

// ---------------- finalize: softmax over L, weighted sum of att ----------------
__global__ __launch_bounds__(256) void finalize_kernel(const float* __restrict__ att,
                                                       const float* __restrict__ spart,
                                                       float* __restrict__ out) {
  int b  = blockIdx.x >> 1;
  int dh = blockIdx.x & 1;
  int t  = threadIdx.x;
  __shared__ float wls[L_];
  __shared__ float red[8];

  float s = -1e30f;
  if (t < L_) {
    const float* sp = spart + (size_t)(b*L_ + t)*16;
    float sum = 0.f;
    #pragma unroll
    for (int p = 0; p < 16; ++p) sum += sp[p];
    s = sum;      // b_d2d omitted: softmax is shift-invariant
  }
  float m = s;
  #pragma unroll
  for (int off = 1; off < 64; off <<= 1) m = fmaxf(m, __shfl_xor(m, off));
  if ((t & 63) == 0) red[t >> 6] = m;
  __syncthreads();
  m = fmaxf(fmaxf(red[0], red[1]), fmaxf(red[2], red[3]));
  float p = (t < L_) ? __expf(s - m) : 0.f;
  float ssum = p;
  #pragma unroll
  for (int off = 1; off < 64; off <<= 1) ssum += __shfl_xor(ssum, off);
  if ((t & 63) == 0) red[4 + (t >> 6)] = ssum;
  __syncthreads();
  float tot = red[4] + red[5] + red[6] + red[7];
  if (t < L_) wls[t] = p / tot;
  __syncthreads();

  int d = dh*512 + t*2;
  const float* abase = att + (size_t)b*L_*D_ + d;
  float a0 = 0.f, a1 = 0.f;
  #pragma unroll 4
  for (int l = 0; l < L_; ++l) {
    float wv = wls[l];
    float2 av = *(const float2*)(abase + (size_t)l*D_);
    a0 += wv*av.x; a1 += wv*av.y;
  }
  float2 o; o.x = a0; o.y = a1;
  *(float2*)(out + (size_t)b*D_ + d) = o;
}

extern "C" void kernel_launch(void* const* d_in, const int* in_sizes, int n_in,
                              void* d_out, int out_size, void* d_ws, size_t ws_size,
                              hipStream_t stream) {
  (void)in_sizes; (void)n_in; (void)out_size; (void)ws_size;
  const float* x   = (const float*)d_in[0];
  const float* att = (const float*)d_in[1];
  const float* h   = (const float*)d_in[2];
  const float* Wa  = (const float*)d_in[3];
  const float* ba  = (const float*)d_in[4];
  const float* Wh  = (const float*)d_in[5];
  const float* bh  = (const float*)d_in[6];
  const float* Wi  = (const float*)d_in[7];
  const float* bi  = (const float*)d_in[8];
  const float* wd  = (const float*)d_in[9];
  // d_in[10] = b_d2d: unused (softmax shift-invariant)

  char* ws = (char*)d_ws;
  ushort_t* att_bf = (ushort_t*)(ws + OFF_ATTBF);
  ushort_t* W_bf   = (ushort_t*)(ws + OFF_WBF);
  ushort_t* A2     = (ushort_t*)(ws + OFF_A2);
  ushort_t* W2     = (ushort_t*)(ws + OFF_W2);
  float*    cmat   = (float*)(ws + OFF_C);
  float*    spart  = (float*)(ws + OFF_SPART);
  float*    out    = (float*)d_out;

  hipLaunchKernelGGL(convert_kernel, dim3(2048), dim3(256), 0, stream,
                     att, Wa, x, h, Wi, Wh, att_bf, W_bf, A2, W2);
  hipLaunchKernelGGL(gemm_kernel<0>, dim3(8), dim3(256), 0, stream,
                     A2, W2, 2048, ba, bh, bi, (const float*)nullptr, wd, cmat, (float*)nullptr);
  hipLaunchKernelGGL(gemm_kernel<1>, dim3(1568), dim3(256), 0, stream,
                     att_bf, W_bf, 1024, ba, bh, bi, cmat, wd, (float*)nullptr, spart);
  hipLaunchKernelGGL(finalize_kernel, dim3(256), dim3(256), 0, stream,
                     att, spart, out);
}